// Round 1
// baseline (404.992 us; speedup 1.0000x reference)
//
#include <hip/hip_runtime.h>

// EdgeEncoding: out[h, q] = (path_len[q] > 0) ? (dot(sums[q], W[h]) / L + b[h]) : 0
// where sums[q] = segment_sum over (pair_id, node_id) of edge_attr[node_id].
//
// Inputs (setup_inputs order):
//   0: x        [N*64]  f32  (UNUSED by the math)
//   1: edge_attr[N*4]   f32
//   2: W        [16*4]  f32
//   3: b        [16]    f32
//   4: pair_id  [P]     i32
//   5: node_id  [P]     i32
//   6: path_len [N*N]   i32
// Output: [16, N, N] f32 (transposed h-major).

__global__ __launch_bounds__(256) void ee_scatter(
    const float* __restrict__ edge_attr,
    const int*   __restrict__ pair_id,
    const int*   __restrict__ node_id,
    float*       __restrict__ sums,
    int P)
{
    int p = blockIdx.x * 256 + threadIdx.x;
    if (p >= P) return;
    int pid = pair_id[p];
    int nid = node_id[p];
    float4 e = reinterpret_cast<const float4*>(edge_attr)[nid];  // 16KB table, L1/L2 resident
    float* s = sums + (size_t)pid * 4;
    atomicAdd(s + 0, e.x);
    atomicAdd(s + 1, e.y);
    atomicAdd(s + 2, e.z);
    atomicAdd(s + 3, e.w);
}

__global__ __launch_bounds__(256) void ee_output(
    const float* __restrict__ sums,       // [NN, 4]
    const int*   __restrict__ path_len,   // [NN]
    const float* __restrict__ W,          // [16, 4]
    const float* __restrict__ b,          // [16]
    float*       __restrict__ out,        // [16, NN]
    int NN)
{
    __shared__ float sW[64];
    __shared__ float sb[16];
    if (threadIdx.x < 64) sW[threadIdx.x] = W[threadIdx.x];
    if (threadIdx.x < 16) sb[threadIdx.x] = b[threadIdx.x];
    __syncthreads();

    int t = blockIdx.x * 256 + threadIdx.x;   // handles pairs [4t, 4t+3]
    if (4 * t >= NN) return;

    const float4* s4 = reinterpret_cast<const float4*>(sums);
    float4 s0 = s4[4 * t + 0];
    float4 s1 = s4[4 * t + 1];
    float4 s2 = s4[4 * t + 2];
    float4 s3 = s4[4 * t + 3];
    int4 L = reinterpret_cast<const int4*>(path_len)[t];

    // f = 1/L (0 if unreachable), g = reachability mask for the bias term.
    float f0 = (L.x > 0) ? 1.0f / (float)L.x : 0.0f;
    float f1 = (L.y > 0) ? 1.0f / (float)L.y : 0.0f;
    float f2 = (L.z > 0) ? 1.0f / (float)L.z : 0.0f;
    float f3 = (L.w > 0) ? 1.0f / (float)L.w : 0.0f;
    float g0 = (L.x > 0) ? 1.0f : 0.0f;
    float g1 = (L.y > 0) ? 1.0f : 0.0f;
    float g2 = (L.z > 0) ? 1.0f : 0.0f;
    float g3 = (L.w > 0) ? 1.0f : 0.0f;

#pragma unroll
    for (int h = 0; h < 16; ++h) {
        float w0 = sW[4 * h + 0];
        float w1 = sW[4 * h + 1];
        float w2 = sW[4 * h + 2];
        float w3 = sW[4 * h + 3];
        float bh = sb[h];
        float4 v;
        v.x = (s0.x * w0 + s0.y * w1 + s0.z * w2 + s0.w * w3) * f0 + bh * g0;
        v.y = (s1.x * w0 + s1.y * w1 + s1.z * w2 + s1.w * w3) * f1 + bh * g1;
        v.z = (s2.x * w0 + s2.y * w1 + s2.z * w2 + s2.w * w3) * f2 + bh * g2;
        v.w = (s3.x * w0 + s3.y * w1 + s3.z * w2 + s3.w * w3) * f3 + bh * g3;
        reinterpret_cast<float4*>(out + (size_t)h * NN)[t] = v;  // coalesced per h-plane
    }
}

extern "C" void kernel_launch(void* const* d_in, const int* in_sizes, int n_in,
                              void* d_out, int out_size, void* d_ws, size_t ws_size,
                              hipStream_t stream) {
    const float* edge_attr = (const float*)d_in[1];
    const float* W         = (const float*)d_in[2];
    const float* b         = (const float*)d_in[3];
    const int*   pair_id   = (const int*)d_in[4];
    const int*   node_id   = (const int*)d_in[5];
    const int*   path_len  = (const int*)d_in[6];
    int P  = in_sizes[4];
    int NN = in_sizes[6];

    float* sums = (float*)d_ws;            // [NN, 4] f32 = 16 MB
    float* out  = (float*)d_out;           // [16, NN]

    // d_ws is re-poisoned to 0xAA before every timed launch — must zero each call.
    hipMemsetAsync(d_ws, 0, (size_t)NN * 4 * sizeof(float), stream);

    int sblocks = (P + 255) / 256;
    ee_scatter<<<sblocks, 256, 0, stream>>>(edge_attr, pair_id, node_id, sums, P);

    int oblocks = (NN / 4 + 255) / 256;
    ee_output<<<oblocks, 256, 0, stream>>>(sums, path_len, W, b, out, NN);
}

// Round 2
// 215.839 us; speedup vs baseline: 1.8764x; 1.8764x over previous
//
#include <hip/hip_runtime.h>

// EdgeEncoding, fused single kernel.
//
// out[h, q] = (path_len[q] > 0) ? (dot(sums[q], W[h]) / L + b[h]) : 0
// where sums[q] = segment_sum over (pair_id, node_id) of edge_attr[node_id].
//
// Key structural fact (from the reference's _build_graph_paths): entries are
// appended source-by-source, so all entries with pid in [s*N, (s+1)*N) are
// CONTIGUOUS, and pair_id[p] / N is globally non-decreasing. Each block owns
// one source s: its 1024 segments fit in 16 KB LDS -> LDS atomics instead of
// device-scope HBM atomics (R0: 296us, WRITE_SIZE=326MB of atomic RMW).
//
// Inputs (setup_inputs order):
//   0: x        [N*64]  f32  (UNUSED)
//   1: edge_attr[N*4]   f32
//   2: W        [16*4]  f32
//   3: b        [16]    f32
//   4: pair_id  [P]     i32
//   5: node_id  [P]     i32
//   6: path_len [N*N]   i32
// Output: [16, N, N] f32.

#define NMAX 1024

__global__ __launch_bounds__(256) void ee_fused(
    const float* __restrict__ edge_attr,
    const float* __restrict__ W,
    const float* __restrict__ b,
    const int*   __restrict__ pair_id,
    const int*   __restrict__ node_id,
    const int*   __restrict__ path_len,
    float*       __restrict__ out,
    int P, int N, int NN)
{
    __shared__ __align__(16) float lsum[NMAX * 4];   // 16 KB
    __shared__ float sW[64];
    __shared__ float sb[16];

    const int tid = threadIdx.x;
    const int s   = blockIdx.x;
    const int n4  = N * 4;

    for (int i = tid; i < n4; i += 256) lsum[i] = 0.0f;
    if (tid < 64) sW[tid] = W[tid];
    if (tid < 16) sb[tid] = b[tid];
    __syncthreads();

    // Binary search the contiguous entry range for source s.
    // Predicate (pair_id[p] >= bound) is monotone in p because pid/N is
    // non-decreasing across the flattened arrays.
    const int lo_bound = s * N;
    const int hi_bound = lo_bound + N;
    int l = 0, r = P;
    while (l < r) { int m = (l + r) >> 1; if (pair_id[m] >= lo_bound) r = m; else l = m + 1; }
    const int lo = l;
    r = P;
    while (l < r) { int m = (l + r) >> 1; if (pair_id[m] >= hi_bound) r = m; else l = m + 1; }
    const int hi = l;

    // Accumulate this source's entries into LDS (ds_add_f32 atomics).
    for (int p = lo + tid; p < hi; p += 256) {
        int pid = pair_id[p];
        int nid = node_id[p];
        float4 e = reinterpret_cast<const float4*>(edge_attr)[nid];  // 16 KB table, L1-resident
        float* dst = lsum + (pid - lo_bound) * 4;
        atomicAdd(dst + 0, e.x);
        atomicAdd(dst + 1, e.y);
        atomicAdd(dst + 2, e.z);
        atomicAdd(dst + 3, e.w);
    }
    __syncthreads();

    // Epilogue: 4 pairs per thread (N == 1024, 256 threads -> one pass).
    const size_t base = (size_t)s * N;
    for (int t = tid; t < N / 4; t += 256) {
        int4 Lv = reinterpret_cast<const int4*>(path_len + base)[t];
        float4 s0 = reinterpret_cast<const float4*>(lsum)[4 * t + 0];
        float4 s1 = reinterpret_cast<const float4*>(lsum)[4 * t + 1];
        float4 s2 = reinterpret_cast<const float4*>(lsum)[4 * t + 2];
        float4 s3 = reinterpret_cast<const float4*>(lsum)[4 * t + 3];

        float f0 = (Lv.x > 0) ? 1.0f / (float)Lv.x : 0.0f;
        float f1 = (Lv.y > 0) ? 1.0f / (float)Lv.y : 0.0f;
        float f2 = (Lv.z > 0) ? 1.0f / (float)Lv.z : 0.0f;
        float f3 = (Lv.w > 0) ? 1.0f / (float)Lv.w : 0.0f;
        float g0 = (Lv.x > 0) ? 1.0f : 0.0f;
        float g1 = (Lv.y > 0) ? 1.0f : 0.0f;
        float g2 = (Lv.z > 0) ? 1.0f : 0.0f;
        float g3 = (Lv.w > 0) ? 1.0f : 0.0f;

#pragma unroll
        for (int h = 0; h < 16; ++h) {
            float w0 = sW[4 * h + 0];
            float w1 = sW[4 * h + 1];
            float w2 = sW[4 * h + 2];
            float w3 = sW[4 * h + 3];
            float bh = sb[h];
            float4 v;
            v.x = (s0.x * w0 + s0.y * w1 + s0.z * w2 + s0.w * w3) * f0 + bh * g0;
            v.y = (s1.x * w0 + s1.y * w1 + s1.z * w2 + s1.w * w3) * f1 + bh * g1;
            v.z = (s2.x * w0 + s2.y * w1 + s2.z * w2 + s2.w * w3) * f2 + bh * g2;
            v.w = (s3.x * w0 + s3.y * w1 + s3.z * w2 + s3.w * w3) * f3 + bh * g3;
            reinterpret_cast<float4*>(out + (size_t)h * NN + base)[t] = v;
        }
    }
}

extern "C" void kernel_launch(void* const* d_in, const int* in_sizes, int n_in,
                              void* d_out, int out_size, void* d_ws, size_t ws_size,
                              hipStream_t stream) {
    const float* edge_attr = (const float*)d_in[1];
    const float* W         = (const float*)d_in[2];
    const float* b         = (const float*)d_in[3];
    const int*   pair_id   = (const int*)d_in[4];
    const int*   node_id   = (const int*)d_in[5];
    const int*   path_len  = (const int*)d_in[6];
    const int P  = in_sizes[4];
    const int NN = in_sizes[6];
    const int N  = in_sizes[0] / 64;       // x is [N, 64]

    float* out = (float*)d_out;            // [16, NN]

    ee_fused<<<N, 256, 0, stream>>>(edge_attr, W, b, pair_id, node_id, path_len,
                                    out, P, N, NN);
}